// Round 1
// baseline (369.427 us; speedup 1.0000x reference)
//
#include <hip/hip_runtime.h>

#define N_NODES 50000
#define N_EDGES 800000
#define IN_DIM  256
#define OUT_DIM 64

// ---------------------------------------------------------------------------
// Kernel 1: support = input @ W   (one 64-lane wave per row; W staged in LDS)
// W layout [k][j] -> LDS read addr (k*64+j)*4: lanes j=0..63 map to banks
// 0..31 twice = 2-way alias, which is free on CDNA4 (m136).
// ---------------------------------------------------------------------------
__global__ __launch_bounds__(256) void gcn_gemm(const float* __restrict__ input,
                                                const float* __restrict__ W,
                                                float* __restrict__ support)
{
    __shared__ float Wlds[IN_DIM * OUT_DIM];   // 64 KiB
    __shared__ float rowbuf[4][IN_DIM];        // 4 KiB (one row per wave)

    // Cooperative W load: 16384 floats / 256 threads = 16 float4 per thread.
    {
        const float4* W4  = (const float4*)W;
        float4*       Wl4 = (float4*)Wlds;
        for (int i = threadIdx.x; i < (IN_DIM * OUT_DIM) / 4; i += 256)
            Wl4[i] = W4[i];
    }
    __syncthreads();

    const int w    = threadIdx.x >> 6;    // wave id in block (0..3)
    const int lane = threadIdx.x & 63;    // output column
    const int gw   = blockIdx.x * 4 + w;
    const int nw   = gridDim.x * 4;

    for (int row = gw; row < N_NODES; row += nw) {
        // Stage this wave's input row into LDS (16 B per lane, coalesced).
        ((float4*)rowbuf[w])[lane] = ((const float4*)(input + (size_t)row * IN_DIM))[lane];
        // Same-wave ds_write -> ds_read: compiler inserts lgkmcnt wait; wave is
        // in lockstep so no __syncthreads needed (and loop trip counts differ
        // across waves, so a barrier here would deadlock anyway).
        float acc = 0.0f;
        #pragma unroll
        for (int k = 0; k < IN_DIM; k += 4) {
            float4 x = *(const float4*)&rowbuf[w][k];   // broadcast read: free
            acc += x.x * Wlds[(k + 0) * OUT_DIM + lane];
            acc += x.y * Wlds[(k + 1) * OUT_DIM + lane];
            acc += x.z * Wlds[(k + 2) * OUT_DIM + lane];
            acc += x.w * Wlds[(k + 3) * OUT_DIM + lane];
        }
        support[(size_t)row * OUT_DIM + lane] = acc;
    }
}

// ---------------------------------------------------------------------------
// Kernel 2: out[n][j] = bias[j]  (pre-fill so the scatter pass is pure atomics)
// ---------------------------------------------------------------------------
__global__ __launch_bounds__(256) void gcn_init(const float* __restrict__ bias,
                                                float* __restrict__ out)
{
    const int total = N_NODES * OUT_DIM;
    for (int i = blockIdx.x * blockDim.x + threadIdx.x; i < total;
         i += gridDim.x * blockDim.x)
        out[i] = bias[i & (OUT_DIM - 1)];
}

// ---------------------------------------------------------------------------
// Kernel 3: for each edge e: out[dst[e]][:] += val[e] * support[src[e]][:]
// One wave per edge; lane j owns column j. Gather (256 B) and atomic (256 B)
// are both fully coalesced. support (12.8 MB) and out (12.8 MB) are
// L3-resident, so this is L2/L3 atomic-throughput bound, not HBM bound.
// ---------------------------------------------------------------------------
__global__ __launch_bounds__(256) void gcn_scatter(const float* __restrict__ support,
                                                   const float* __restrict__ val,
                                                   const int*   __restrict__ src,
                                                   const int*   __restrict__ dst,
                                                   float* __restrict__ out)
{
    const int lane   = threadIdx.x & 63;
    const int gw     = (blockIdx.x * blockDim.x + threadIdx.x) >> 6;
    const int nwaves = (gridDim.x * blockDim.x) >> 6;

    for (int e = gw; e < N_EDGES; e += nwaves) {
        const int   s = src[e];          // wave-uniform broadcast loads
        const int   d = dst[e];
        const float v = val[e];
        const float m = support[(size_t)s * OUT_DIM + lane] * v;
        atomicAdd(&out[(size_t)d * OUT_DIM + lane], m);
    }
}

// ---------------------------------------------------------------------------
extern "C" void kernel_launch(void* const* d_in, const int* in_sizes, int n_in,
                              void* d_out, int out_size, void* d_ws, size_t ws_size,
                              hipStream_t stream)
{
    const float* input  = (const float*)d_in[0];
    const float* weight = (const float*)d_in[1];
    const float* bias   = (const float*)d_in[2];
    const float* eval_  = (const float*)d_in[3];
    const int*   esrc   = (const int*)d_in[4];
    const int*   edst   = (const int*)d_in[5];
    float*       out    = (float*)d_out;

    float* support = (float*)d_ws;   // 50000*64*4 = 12.8 MB scratch

    // 1) support = X @ W
    gcn_gemm<<<2048, 256, 0, stream>>>(input, weight, support);
    // 2) out = bias (broadcast)
    gcn_init<<<2048, 256, 0, stream>>>(bias, out);
    // 3) scatter-add messages
    gcn_scatter<<<2048, 256, 0, stream>>>(support, eval_, esrc, edst, out);
}